// Round 13
// baseline (104.132 us; speedup 1.0000x reference)
//
#include <hip/hip_runtime.h>
#include <math.h>
#include <stdint.h>

namespace {
constexpr int B = 32, Q = 48, A = 48, D = 300;
constexpr int C = 512, K = 5, H = 512, P = 512, NCLS = 2;
constexpr int CK = C * K;         // 2560
constexpr int M = B * Q;          // 1536
constexpr int KP = 320;           // K padded for bf16 MFMA
constexpr float EPS_COS = 1e-6f, EPS_BN = 1e-5f;
constexpr int NPAN = 96 + 96 + 160 + 160;   // 512 16-row panels to convert
constexpr int NCOS = M / 4;                 // 384
constexpr int NJ = 8;                       // proj j-chunks
constexpr int PSZ = 40 * 16 * 8;            // 5120 shorts per panel
}
using short8 = __attribute__((ext_vector_type(8))) short;
using f32x4  = __attribute__((ext_vector_type(4))) float;

__device__ inline short f2bf(float v) {
  uint32_t u = __builtin_bit_cast(uint32_t, v);
  return (short)((u + 0x7fffu + ((u >> 16) & 1u)) >> 16);  // RNE
}

// ---------------------------------------------------------------------------
// prep: [0,512) fragment-major bf16 panel convert (LDS-staged, coalesced both
// sides) | [512,896) cosine sim
// ---------------------------------------------------------------------------
__global__ void prep_k(const float* __restrict__ q, const float* __restrict__ a,
                       const float* __restrict__ smw, const float* __restrict__ ctxw,
                       short* __restrict__ qb, short* __restrict__ ab,
                       short* __restrict__ smb, short* __restrict__ ctxb,
                       float* __restrict__ cosm) {
  __shared__ float sa[16 * 300];    // 19.2 KB panel stage
  __shared__ float4 qrow4[300];
  const int vb = blockIdx.x, tid = threadIdx.x;
  if (vb < NPAN) {
    const float* src; short* dst; int pl;
    if (vb < 96)       { src = q;    dst = qb;   pl = vb; }
    else if (vb < 192) { src = a;    dst = ab;   pl = vb - 96; }
    else if (vb < 352) { src = smw;  dst = smb;  pl = vb - 192; }
    else               { src = ctxw; dst = ctxb; pl = vb - 352; }
    const int row0 = pl * 16;
    for (int i = tid; i < 1200; i += 256) {
      const int r = i / 75, c4 = i - r * 75;
      const float4 v = *(const float4*)&src[(size_t)(row0 + r) * D + c4 * 4];
      *(float4*)&sa[r * 300 + c4 * 4] = v;
    }
    __syncthreads();
    for (int it = tid; it < 640; it += 256) {
      const int k8 = it >> 4, r = it & 15;
      short tmp[8];
#pragma unroll
      for (int e = 0; e < 8; ++e) {
        const int k = k8 * 8 + e;
        tmp[e] = (k < D) ? f2bf(sa[r * 300 + k]) : (short)0;
      }
      *(int4*)&dst[(size_t)pl * PSZ + (size_t)k8 * 128 + r * 8] = *(const int4*)tmp;
    }
  } else {
    const int b5 = vb - NPAN;
    const int qq = b5 * 4;            // 4 q-rows, same b (48 % 4 == 0)
    const int b = qq / Q;
    const float4* qp4 = (const float4*)(q + (size_t)qq * D);
    for (int i = tid; i < 300; i += 256) qrow4[i] = qp4[i];
    __syncthreads();
    const int sub = tid >> 6, lane = tid & 63;
    float qsq = 0.f;
    for (int i = lane; i < 75; i += 64) {
      float4 v = qrow4[sub * 75 + i];
      qsq += v.x * v.x + v.y * v.y + v.z * v.z + v.w * v.w;
    }
#pragma unroll
    for (int off2 = 32; off2; off2 >>= 1) qsq += __shfl_xor(qsq, off2);
    const float qn = sqrtf(qsq);
    if (lane < A) {
      const float4* ap4 = (const float4*)(a + ((size_t)b * A + lane) * D);
      float dot = 0.f, asq = 0.f;
      for (int i = 0; i < 75; ++i) {
        float4 av = ap4[i], qv = qrow4[sub * 75 + i];
        dot += qv.x * av.x + qv.y * av.y + qv.z * av.z + qv.w * av.w;
        asq += av.x * av.x + av.y * av.y + av.z * av.z + av.w * av.w;
      }
      cosm[(size_t)(qq + sub) * A + lane] = dot / fmaxf(qn * sqrtf(asq), EPS_COS);
    }
  }
}

// ---------------------------------------------------------------------------
// fused: [0,256) ctx GEMM+pool | [256,512) sm 2x(GEMM+pool) | [512,1792)
// weight transposes.  Grid = 512 GEMM blocks = exactly 2/CU, one round.
// Coalesced fragment-major loads, 2-deep prefetch, fp32 S in [4][56][81],
// bf16 cos.  80000 B LDS.
// ---------------------------------------------------------------------------
__global__ void __launch_bounds__(256)
fused_k(const short* __restrict__ qb, const short* __restrict__ ab,
        const short* __restrict__ smb, const short* __restrict__ ctxb,
        const float* __restrict__ cosm, const float* __restrict__ smbias,
        const float* __restrict__ ctxbias,
        const float* __restrict__ projw, const float* __restrict__ smfcw,
        const float* __restrict__ ctxfcw,
        float* __restrict__ projT, float* __restrict__ smfcwT,
        float* __restrict__ ctxfcwT,
        float* __restrict__ pooled, float* __restrict__ pbar) {
  __shared__ __align__(16) char Lraw[80000];
  const int vb = blockIdx.x, tid = threadIdx.x;

  if (vb >= 512) {  // ---------------- transpose blocks ----------------
    float (*tile)[33] = (float (*)[33])Lraw;
    const int vb2 = vb - 512;
    const int tx = tid & 31, ty = tid >> 5;
    if (vb2 < 768) {  // projT
      const int j0 = (vb2 % 48) * 32, p0 = (vb2 / 48) * 32;
      for (int i = ty; i < 32; i += 8)
        tile[i][tx] = projw[(size_t)(p0 + i) * (3 * H) + j0 + tx];
      __syncthreads();
      for (int i = ty; i < 32; i += 8)
        projT[(size_t)(j0 + i) * P + p0 + tx] = tile[tx][i];
    } else {
      const int b3 = vb2 - 768;
      const bool isC = b3 >= 256;
      const int b4 = isC ? b3 - 256 : b3;
      const float* W = isC ? ctxfcw : smfcw;
      float* WT = isC ? ctxfcwT : smfcwT;
      const int c0 = (b4 % 16) * 32, h0 = (b4 / 16) * 32;
      for (int i = ty; i < 32; i += 8)
        tile[i][tx] = W[(size_t)(h0 + i) * C + c0 + tx];
      __syncthreads();
      for (int i = ty; i < 32; i += 8)
        WT[(size_t)(c0 + i) * H + h0 + tx] = tile[tx][i];
    }
    return;
  }

  // ---------------- GEMM + pool blocks ----------------
  float (*Sl)[56][81] = (float (*)[56][81])Lraw;          // 72576 B
  short (*coslb)[56]  = (short (*)[56])(Lraw + 72576);    // 5376 B
  float* redf         = (float*)(Lraw + 77952);           // 2048 B
  const bool isCtx = vb < 256;
  const int lane = tid & 63, wv = tid >> 6;
  const int r16 = lane & 15, kq = lane >> 4;
  const int cgi = (isCtx ? vb : vb - 256) & 7;

  const short* Wp = isCtx ? ctxb : smb;
  const int wp0 = cgi * 20 + wv * 5;
  const short* Ww = Wp + (size_t)wp0 * PSZ + kq * 128 + r16 * 8;

  for (int i = lane; i < 640; i += 64) {  // zero-pad rows 0..3, 52..55
    const int rr = i / 80, cc2 = i % 80;
    Sl[wv][rr < 4 ? rr : rr + 48][cc2] = 0.f;
  }

  f32x4 acc[3][5];
  int4 cA0[3], cB0[5], cA1[3], cB1[5];

  auto kloop = [&](const short* Xw) {
#pragma unroll
    for (int mi = 0; mi < 3; ++mi)
#pragma unroll
      for (int ni = 0; ni < 5; ++ni) acc[mi][ni] = f32x4{0.f, 0.f, 0.f, 0.f};
    auto issue = [&](int ks, int4* pA, int4* pB) {
#pragma unroll
      for (int i = 0; i < 3; ++i) pA[i] = *(const int4*)(Xw + (size_t)i * PSZ + ks * 512);
#pragma unroll
      for (int i = 0; i < 5; ++i) pB[i] = *(const int4*)(Ww + (size_t)i * PSZ + ks * 512);
    };
    auto domfma = [&](const int4* pA, const int4* pB) {
#pragma unroll
      for (int mi = 0; mi < 3; ++mi)
#pragma unroll
        for (int ni = 0; ni < 5; ++ni)
          acc[mi][ni] = __builtin_amdgcn_mfma_f32_16x16x32_bf16(
              __builtin_bit_cast(short8, pA[mi]),
              __builtin_bit_cast(short8, pB[ni]), acc[mi][ni], 0, 0, 0);
    };
    issue(0, cA0, cB0);
    issue(1, cA1, cB1);
#pragma unroll
    for (int ks2 = 0; ks2 < 5; ++ks2) {
      const int ks = 2 * ks2;
      domfma(cA0, cB0);
      if (ks + 2 < 10) issue(ks + 2, cA0, cB0);
      domfma(cA1, cB1);
      if (ks + 3 < 10) issue(ks + 3, cA1, cB1);
    }
#pragma unroll
    for (int mi = 0; mi < 3; ++mi)
#pragma unroll
      for (int ni = 0; ni < 5; ++ni)
#pragma unroll
        for (int r = 0; r < 4; ++r)
          Sl[wv][mi * 16 + kq * 4 + r + 4][ni * 16 + r16] = acc[mi][ni][r];
  };

  if (!isCtx) {
    const int m2 = (vb - 256) >> 3;
#pragma unroll 1
    for (int u = 0; u < 2; ++u) {
      const int n = 2 * m2 + u;
      const short* Xp = (n < B) ? qb + (size_t)n * 3 * PSZ
                                : ab + (size_t)(n - B) * 3 * PSZ;
      kloop(Xp + kq * 128 + r16 * 8);
      __syncthreads();
      // sm pool
      const int ch = tid & 63, part = tid >> 6;
      const int w2 = ch >> 4, cl = (ch & 15) * 5;
      float best = -1e30f;
#pragma unroll
      for (int j = 0; j < 13; ++j) {
        const int l = part * 13 + j;
        const float z = Sl[w2][l + 0][cl + 0] + Sl[w2][l + 1][cl + 1]
                      + Sl[w2][l + 2][cl + 2] + Sl[w2][l + 3][cl + 3]
                      + Sl[w2][l + 4][cl + 4];
        best = fmaxf(best, z);
      }
      redf[part * 64 + ch] = best;
      __syncthreads();   // also guarantees all Sl reads done before next dump
      if (tid < 64) {
        const float m = fmaxf(fmaxf(redf[tid], redf[64 + tid]),
                              fmaxf(redf[128 + tid], redf[192 + tid]));
        pooled[(size_t)n * C + cgi * 64 + tid] =
            fmaxf(m + smbias[cgi * 64 + tid], 0.f);
      }
    }
  } else {
    const int nb = vb >> 3;
    for (int i = tid; i < 48 * 56; i += 256) {  // stage cos (bf16), padded
      const int qi = i / 56, p4 = i % 56;
      const float cv = (p4 >= 4 && p4 < 52)
                     ? cosm[((size_t)nb * Q + qi) * A + p4 - 4] : 0.f;
      coslb[qi][p4] = f2bf(cv);
    }
    kloop(ab + (size_t)nb * 3 * PSZ + kq * 128 + r16 * 8);
    __syncthreads();
    const int clane = tid & 31, grp = tid >> 5;
    float best[2][6];
#pragma unroll
    for (int cc = 0; cc < 2; ++cc)
#pragma unroll
      for (int j = 0; j < 6; ++j) best[cc][j] = -1e30f;
    for (int ch13 = 0; ch13 < 13; ++ch13) {
      float cw[6][8];
#pragma unroll
      for (int j = 0; j < 6; ++j) {
        const short* crow = &coslb[grp * 6 + j][4 * ch13];
        const int2 w0 = *(const int2*)crow;
        const int2 w1 = *(const int2*)(crow + 4);
        cw[j][0] = __builtin_bit_cast(float, w0.x << 16);
        cw[j][1] = __builtin_bit_cast(float, (int)(w0.x & 0xffff0000));
        cw[j][2] = __builtin_bit_cast(float, w0.y << 16);
        cw[j][3] = __builtin_bit_cast(float, (int)(w0.y & 0xffff0000));
        cw[j][4] = __builtin_bit_cast(float, w1.x << 16);
        cw[j][5] = __builtin_bit_cast(float, (int)(w1.x & 0xffff0000));
        cw[j][6] = __builtin_bit_cast(float, w1.y << 16);
        cw[j][7] = __builtin_bit_cast(float, (int)(w1.y & 0xffff0000));
      }
#pragma unroll
      for (int cc = 0; cc < 2; ++cc) {
        const int ch = cc * 32 + clane;
        const int w2 = ch >> 4, cl = (ch & 15) * 5;
        float sk[4][5];
#pragma unroll
        for (int p = 0; p < 4; ++p)
#pragma unroll
          for (int k = 0; k < K; ++k)
            sk[p][k] = Sl[w2][4 * ch13 + p + k][cl + k];
#pragma unroll
        for (int p = 0; p < 4; ++p)
#pragma unroll
          for (int j = 0; j < 6; ++j) {
            float zv = 0.f;
#pragma unroll
            for (int k = 0; k < K; ++k) zv += cw[j][p + k] * sk[p][k];
            best[cc][j] = fmaxf(best[cc][j], zv);
          }
      }
    }
#pragma unroll
    for (int cc = 0; cc < 2; ++cc) {
      const float bc = ctxbias[cgi * 64 + cc * 32 + clane];
      float s = 0.f;
#pragma unroll
      for (int j = 0; j < 6; ++j) s += fmaxf(best[cc][j] + bc, 0.f);
      redf[cc * 256 + grp * 32 + clane] = s;
    }
    __syncthreads();
    if (tid < 64) {
      const int cc = tid >> 5, cl2 = tid & 31;
      float tot = 0.f;
#pragma unroll
      for (int g = 0; g < 8; ++g) tot += redf[cc * 256 + g * 32 + cl2];
      pbar[(size_t)nb * C + cgi * 64 + cc * 32 + cl2] = tot * (1.0f / Q);
    }
  }
}

// ---------------------------------------------------------------------------
// projfc: recompute the 192 FC outputs this block needs, then proj partial.
// ---------------------------------------------------------------------------
__global__ void projfc_k(const float* __restrict__ pooled, const float* __restrict__ pbar,
                         const float* __restrict__ smfcwT, const float* __restrict__ smfcb,
                         const float* __restrict__ ctxfcwT, const float* __restrict__ ctxfcb,
                         const float* __restrict__ projT, float* __restrict__ partial) {
  __shared__ float rows[3 * C];
  __shared__ float cs[192];
  const int b = blockIdx.x, g = blockIdx.y, tid = threadIdx.x;
  for (int i = tid; i < C; i += 256) {
    rows[i] = pooled[(size_t)b * C + i];
    rows[C + i] = pooled[(size_t)(B + b) * C + i];
    rows[2 * C + i] = pbar[(size_t)b * C + i];
  }
  __syncthreads();
  if (tid < 192) {
    const int j = g * 192 + tid;
    const int seg = j >> 9, h = j & 511;
    const float* WT = (seg == 2) ? ctxfcwT : smfcwT;
    const float* in = rows + seg * C;
    float acc = (seg == 2) ? ctxfcb[h] : smfcb[h];
    for (int c = 0; c < C; ++c) acc += in[c] * WT[(size_t)c * H + h];
    cs[tid] = acc;
  }
  __syncthreads();
  const int js = g * 192;
  float a0 = 0.f, a1 = 0.f;
  for (int j = 0; j < 192; ++j) {
    const float c = cs[j];
    a0 += c * projT[(size_t)(js + j) * P + tid];
    a1 += c * projT[(size_t)(js + j) * P + tid + 256];
  }
  partial[((size_t)g * B + b) * P + tid] = a0;
  partial[((size_t)g * B + b) * P + tid + 256] = a1;
}

// ---------------------------------------------------------------------------
// bnmid: sum proj partials; batch stats over B; tanh -> t.
// ---------------------------------------------------------------------------
__global__ void bnmid_k(const float* __restrict__ partial, const float* __restrict__ proj_b,
                        const float* __restrict__ gamma, const float* __restrict__ beta,
                        float* __restrict__ t) {
  __shared__ float s1[256], s2[256];
  const int pl = threadIdx.x & 63, rg = threadIdx.x >> 6;
  const int p = blockIdx.x * 64 + pl;
  const float pb = proj_b[p];
  float v[8];
#pragma unroll
  for (int i = 0; i < 8; ++i) {
    const int r = rg * 8 + i;
    float s = pb;
#pragma unroll
    for (int g = 0; g < NJ; ++g) s += partial[((size_t)g * B + r) * P + p];
    v[i] = s;
  }
  float a = 0.f;
#pragma unroll
  for (int i = 0; i < 8; ++i) a += v[i];
  s1[rg * 64 + pl] = a;
  __syncthreads();
  const float mu = (s1[pl] + s1[64 + pl] + s1[128 + pl] + s1[192 + pl]) * (1.0f / B);
  float b2 = 0.f;
#pragma unroll
  for (int i = 0; i < 8; ++i) { const float d = v[i] - mu; b2 += d * d; }
  s2[rg * 64 + pl] = b2;
  __syncthreads();
  const float var = (s2[pl] + s2[64 + pl] + s2[128 + pl] + s2[192 + pl]) * (1.0f / B);
  const float inv = rsqrtf(var + EPS_BN);
  const float g = gamma[p], be = beta[p];
#pragma unroll
  for (int i = 0; i < 8; ++i)
    t[(size_t)(rg * 8 + i) * P + p] = tanhf((v[i] - mu) * inv * g + be);
}

// ---------------------------------------------------------------------------
// final FC
// ---------------------------------------------------------------------------
__global__ void out_k(const float* __restrict__ t, const float* __restrict__ W,
                      const float* __restrict__ bias, float* __restrict__ out) {
  const int tid = threadIdx.x;  // 512
  const int o = tid >> 3, lane8 = tid & 7;
  const int bb = o >> 1, cl = o & 1;
  float acc = 0.f;
  for (int j = lane8; j < P; j += 8) acc += t[(size_t)bb * P + j] * W[cl * P + j];
#pragma unroll
  for (int off = 4; off; off >>= 1) acc += __shfl_down(acc, off);
  if (lane8 == 0) out[bb * NCLS + cl] = acc + bias[cl];
}

extern "C" void kernel_launch(void* const* d_in, const int* in_sizes, int n_in,
                              void* d_out, int out_size, void* d_ws, size_t ws_size,
                              hipStream_t stream) {
  const float* q       = (const float*)d_in[0];
  const float* a       = (const float*)d_in[1];
  const float* sm_w    = (const float*)d_in[2];
  const float* sm_b    = (const float*)d_in[3];
  const float* sm_fcw  = (const float*)d_in[4];
  const float* sm_fcb  = (const float*)d_in[5];
  const float* ctx_w   = (const float*)d_in[6];
  const float* ctx_b   = (const float*)d_in[7];
  const float* ctx_fcw = (const float*)d_in[8];
  const float* ctx_fcb = (const float*)d_in[9];
  const float* proj_w  = (const float*)d_in[10];
  const float* proj_b  = (const float*)d_in[11];
  const float* gamma   = (const float*)d_in[12];
  const float* beta    = (const float*)d_in[13];
  const float* out_w   = (const float*)d_in[14];
  const float* out_b   = (const float*)d_in[15];

  float* ws = (float*)d_ws;
  size_t off = 0;
  auto alloc = [&](size_t n) { float* p = ws + off; off += n; return p; };
  float* projT   = alloc((size_t)3 * H * P);
  float* smfcwT  = alloc((size_t)C * H);
  float* ctxfcwT = alloc((size_t)C * H);
  float* cosm    = alloc((size_t)B * Q * A);
  float* pooled  = alloc((size_t)2 * B * C);
  float* pbar    = alloc((size_t)B * C);
  float* partial = alloc((size_t)NJ * B * P);
  float* tbuf    = alloc((size_t)B * P);
  short* qb      = (short*)alloc((size_t)M * KP / 2);
  short* ab      = (short*)alloc((size_t)M * KP / 2);
  short* smb2    = (short*)alloc((size_t)CK * KP / 2);
  short* ctxb2   = (short*)alloc((size_t)CK * KP / 2);

  prep_k<<<NPAN + NCOS, 256, 0, stream>>>(q, a, sm_w, ctx_w, qb, ab, smb2, ctxb2, cosm);
  fused_k<<<1792, 256, 0, stream>>>(qb, ab, smb2, ctxb2, cosm, sm_b, ctx_b,
                                    proj_w, sm_fcw, ctx_fcw, projT, smfcwT, ctxfcwT,
                                    pooled, pbar);
  projfc_k<<<dim3(B, NJ), 256, 0, stream>>>(pooled, pbar, smfcwT, sm_fcb,
                                            ctxfcwT, ctx_fcb, projT, partial);
  bnmid_k<<<P / 64, 256, 0, stream>>>(partial, proj_b, gamma, beta, tbuf);
  out_k<<<1, 512, 0, stream>>>(tbuf, out_w, out_b, (float*)d_out);
}

// Round 14
// 88.840 us; speedup vs baseline: 1.1721x; 1.1721x over previous
//
#include <hip/hip_runtime.h>
#include <math.h>
#include <stdint.h>

namespace {
constexpr int B = 32, Q = 48, A = 48, D = 300;
constexpr int C = 512, K = 5, H = 512, P = 512, NCLS = 2;
constexpr int CK = C * K;         // 2560
constexpr int M = B * Q;          // 1536
constexpr int KP = 320;           // K padded for bf16 MFMA
constexpr float EPS_COS = 1e-6f, EPS_BN = 1e-5f;
constexpr int NPAN = 96 + 96 + 160 + 160;   // 512 16-row panels to convert
constexpr int NCOS = M / 4;                 // 384
constexpr int NJ = 8;                       // proj j-chunks
constexpr int PSZ = 40 * 16 * 8;            // 5120 shorts per panel
}
using short8 = __attribute__((ext_vector_type(8))) short;
using f32x4  = __attribute__((ext_vector_type(4))) float;

__device__ inline short f2bf(float v) {
  uint32_t u = __builtin_bit_cast(uint32_t, v);
  return (short)((u + 0x7fffu + ((u >> 16) & 1u)) >> 16);  // RNE
}

// ---------------------------------------------------------------------------
// prep: [0,512) fragment-major bf16 panel convert (LDS-staged, coalesced both
// sides) | [512,896) cosine sim
// ---------------------------------------------------------------------------
__global__ void prep_k(const float* __restrict__ q, const float* __restrict__ a,
                       const float* __restrict__ smw, const float* __restrict__ ctxw,
                       short* __restrict__ qb, short* __restrict__ ab,
                       short* __restrict__ smb, short* __restrict__ ctxb,
                       float* __restrict__ cosm) {
  __shared__ float sa[16 * 300];    // 19.2 KB panel stage
  __shared__ float4 qrow4[300];
  const int vb = blockIdx.x, tid = threadIdx.x;
  if (vb < NPAN) {
    const float* src; short* dst; int pl;
    if (vb < 96)       { src = q;    dst = qb;   pl = vb; }
    else if (vb < 192) { src = a;    dst = ab;   pl = vb - 96; }
    else if (vb < 352) { src = smw;  dst = smb;  pl = vb - 192; }
    else               { src = ctxw; dst = ctxb; pl = vb - 352; }
    const int row0 = pl * 16;
    for (int i = tid; i < 1200; i += 256) {
      const int r = i / 75, c4 = i - r * 75;
      const float4 v = *(const float4*)&src[(size_t)(row0 + r) * D + c4 * 4];
      *(float4*)&sa[r * 300 + c4 * 4] = v;
    }
    __syncthreads();
    for (int it = tid; it < 640; it += 256) {
      const int k8 = it >> 4, r = it & 15;
      short tmp[8];
#pragma unroll
      for (int e = 0; e < 8; ++e) {
        const int k = k8 * 8 + e;
        tmp[e] = (k < D) ? f2bf(sa[r * 300 + k]) : (short)0;
      }
      *(int4*)&dst[(size_t)pl * PSZ + (size_t)k8 * 128 + r * 8] = *(const int4*)tmp;
    }
  } else {
    const int b5 = vb - NPAN;
    const int qq = b5 * 4;            // 4 q-rows, same b (48 % 4 == 0)
    const int b = qq / Q;
    const float4* qp4 = (const float4*)(q + (size_t)qq * D);
    for (int i = tid; i < 300; i += 256) qrow4[i] = qp4[i];
    __syncthreads();
    const int sub = tid >> 6, lane = tid & 63;
    float qsq = 0.f;
    for (int i = lane; i < 75; i += 64) {
      float4 v = qrow4[sub * 75 + i];
      qsq += v.x * v.x + v.y * v.y + v.z * v.z + v.w * v.w;
    }
#pragma unroll
    for (int off2 = 32; off2; off2 >>= 1) qsq += __shfl_xor(qsq, off2);
    const float qn = sqrtf(qsq);
    if (lane < A) {
      const float4* ap4 = (const float4*)(a + ((size_t)b * A + lane) * D);
      float dot = 0.f, asq = 0.f;
      for (int i = 0; i < 75; ++i) {
        float4 av = ap4[i], qv = qrow4[sub * 75 + i];
        dot += qv.x * av.x + qv.y * av.y + qv.z * av.z + qv.w * av.w;
        asq += av.x * av.x + av.y * av.y + av.z * av.z + av.w * av.w;
      }
      cosm[(size_t)(qq + sub) * A + lane] = dot / fmaxf(qn * sqrtf(asq), EPS_COS);
    }
  }
}

// ---------------------------------------------------------------------------
// fused: [0,512) ctx GEMM + HALF-pool (q' split; 32b x 8cg x 2half) |
// [512,1024) sm GEMM+pool | [1024,2304) weight transposes.
// 1024 GEMM blocks of near-uniform cost = 2 clean rounds at 2 blocks/CU.
// Coalesced fragment-major loads, 2-deep prefetch, fp32 S in [4][56][81].
// ---------------------------------------------------------------------------
__global__ void __launch_bounds__(256)
fused_k(const short* __restrict__ qb, const short* __restrict__ ab,
        const short* __restrict__ smb, const short* __restrict__ ctxb,
        const float* __restrict__ cosm, const float* __restrict__ smbias,
        const float* __restrict__ ctxbias,
        const float* __restrict__ projw, const float* __restrict__ smfcw,
        const float* __restrict__ ctxfcw,
        float* __restrict__ projT, float* __restrict__ smfcwT,
        float* __restrict__ ctxfcwT,
        float* __restrict__ pooled, float* __restrict__ pbarH) {
  __shared__ __align__(16) char Lraw[80000];
  const int vb = blockIdx.x, tid = threadIdx.x;

  if (vb >= 1024) {  // ---------------- transpose blocks ----------------
    float (*tile)[33] = (float (*)[33])Lraw;
    const int vb2 = vb - 1024;
    const int tx = tid & 31, ty = tid >> 5;
    if (vb2 < 768) {  // projT
      const int j0 = (vb2 % 48) * 32, p0 = (vb2 / 48) * 32;
      for (int i = ty; i < 32; i += 8)
        tile[i][tx] = projw[(size_t)(p0 + i) * (3 * H) + j0 + tx];
      __syncthreads();
      for (int i = ty; i < 32; i += 8)
        projT[(size_t)(j0 + i) * P + p0 + tx] = tile[tx][i];
    } else {
      const int b3 = vb2 - 768;
      const bool isC = b3 >= 256;
      const int b4 = isC ? b3 - 256 : b3;
      const float* W = isC ? ctxfcw : smfcw;
      float* WT = isC ? ctxfcwT : smfcwT;
      const int c0 = (b4 % 16) * 32, h0 = (b4 / 16) * 32;
      for (int i = ty; i < 32; i += 8)
        tile[i][tx] = W[(size_t)(h0 + i) * C + c0 + tx];
      __syncthreads();
      for (int i = ty; i < 32; i += 8)
        WT[(size_t)(c0 + i) * H + h0 + tx] = tile[tx][i];
    }
    return;
  }

  // ---------------- GEMM + pool blocks ----------------
  float (*Sl)[56][81] = (float (*)[56][81])Lraw;          // 72576 B
  short (*coslb)[56]  = (short (*)[56])(Lraw + 72576);    // 2688 B (24 rows)
  float* redf         = (float*)(Lraw + 75648);           // 2048 B
  const bool isCtx = vb < 512;
  const int lane = tid & 63, wv = tid >> 6;
  const int r16 = lane & 15, kq = lane >> 4;
  // ctx: vb = b*16 + cgi*2 + half ;  sm: (vb-512) = n*8 + cgi
  const int nb   = isCtx ? (vb >> 4) : ((vb - 512) >> 3);
  const int cgi  = isCtx ? ((vb >> 1) & 7) : ((vb - 512) & 7);
  const int half = isCtx ? (vb & 1) : 0;

  const short* Wp = isCtx ? ctxb : smb;
  const int wp0 = cgi * 20 + wv * 5;
  const short* Ww = Wp + (size_t)wp0 * PSZ + kq * 128 + r16 * 8;
  const short* Xp = isCtx ? (ab + (size_t)nb * 3 * PSZ)
      : ((nb < B) ? qb + (size_t)nb * 3 * PSZ : ab + (size_t)(nb - B) * 3 * PSZ);
  const short* Xw = Xp + kq * 128 + r16 * 8;

  for (int i = lane; i < 640; i += 64) {  // zero-pad rows 0..3, 52..55
    const int rr = i / 80, cc2 = i % 80;
    Sl[wv][rr < 4 ? rr : rr + 48][cc2] = 0.f;
  }
  if (isCtx) {  // stage 24 cos rows (bf16), zero-padded position axis
    for (int i = tid; i < 24 * 56; i += 256) {
      const int ql = i / 56, p4 = i % 56;
      const int qi = half * 24 + ql;
      const float cv = (p4 >= 4 && p4 < 52)
                     ? cosm[((size_t)nb * Q + qi) * A + p4 - 4] : 0.f;
      coslb[ql][p4] = f2bf(cv);
    }
  }

  f32x4 acc[3][5];
#pragma unroll
  for (int mi = 0; mi < 3; ++mi)
#pragma unroll
    for (int ni = 0; ni < 5; ++ni) acc[mi][ni] = f32x4{0.f, 0.f, 0.f, 0.f};

  int4 cA0[3], cB0[5], cA1[3], cB1[5];
  auto issue = [&](int ks, int4* pA, int4* pB) {
#pragma unroll
    for (int i = 0; i < 3; ++i) pA[i] = *(const int4*)(Xw + (size_t)i * PSZ + ks * 512);
#pragma unroll
    for (int i = 0; i < 5; ++i) pB[i] = *(const int4*)(Ww + (size_t)i * PSZ + ks * 512);
  };
  auto domfma = [&](const int4* pA, const int4* pB) {
#pragma unroll
    for (int mi = 0; mi < 3; ++mi)
#pragma unroll
      for (int ni = 0; ni < 5; ++ni)
        acc[mi][ni] = __builtin_amdgcn_mfma_f32_16x16x32_bf16(
            __builtin_bit_cast(short8, pA[mi]),
            __builtin_bit_cast(short8, pB[ni]), acc[mi][ni], 0, 0, 0);
  };

  issue(0, cA0, cB0);
  issue(1, cA1, cB1);
#pragma unroll
  for (int ks2 = 0; ks2 < 5; ++ks2) {
    const int ks = 2 * ks2;
    domfma(cA0, cB0);
    if (ks + 2 < 10) issue(ks + 2, cA0, cB0);
    domfma(cA1, cB1);
    if (ks + 3 < 10) issue(ks + 3, cA1, cB1);
  }
#pragma unroll
  for (int mi = 0; mi < 3; ++mi)
#pragma unroll
    for (int ni = 0; ni < 5; ++ni)
#pragma unroll
      for (int r = 0; r < 4; ++r)
        Sl[wv][mi * 16 + kq * 4 + r + 4][ni * 16 + r16] = acc[mi][ni][r];
  __syncthreads();

  if (!isCtx) {
    const int ch = tid & 63, part = tid >> 6;
    const int w2 = ch >> 4, cl = (ch & 15) * 5;
    float best = -1e30f;
#pragma unroll
    for (int j = 0; j < 13; ++j) {
      const int l = part * 13 + j;
      const float z = Sl[w2][l + 0][cl + 0] + Sl[w2][l + 1][cl + 1]
                    + Sl[w2][l + 2][cl + 2] + Sl[w2][l + 3][cl + 3]
                    + Sl[w2][l + 4][cl + 4];
      best = fmaxf(best, z);
    }
    redf[part * 64 + ch] = best;
    __syncthreads();
    if (tid < 64) {
      const float m = fmaxf(fmaxf(redf[tid], redf[64 + tid]),
                            fmaxf(redf[128 + tid], redf[192 + tid]));
      pooled[(size_t)nb * C + cgi * 64 + tid] =
          fmaxf(m + smbias[cgi * 64 + tid], 0.f);
    }
  } else {
    // half-pool: 8 grp x 3 q' each x 2 channels
    const int clane = tid & 31, grp = tid >> 5;
    float best[2][3];
#pragma unroll
    for (int cc = 0; cc < 2; ++cc)
#pragma unroll
      for (int j = 0; j < 3; ++j) best[cc][j] = -1e30f;
    for (int ch13 = 0; ch13 < 13; ++ch13) {
      float cw[3][8];
#pragma unroll
      for (int j = 0; j < 3; ++j) {
        const short* crow = &coslb[grp * 3 + j][4 * ch13];
        const int2 w0 = *(const int2*)crow;
        const int2 w1 = *(const int2*)(crow + 4);
        cw[j][0] = __builtin_bit_cast(float, w0.x << 16);
        cw[j][1] = __builtin_bit_cast(float, (int)(w0.x & 0xffff0000));
        cw[j][2] = __builtin_bit_cast(float, w0.y << 16);
        cw[j][3] = __builtin_bit_cast(float, (int)(w0.y & 0xffff0000));
        cw[j][4] = __builtin_bit_cast(float, w1.x << 16);
        cw[j][5] = __builtin_bit_cast(float, (int)(w1.x & 0xffff0000));
        cw[j][6] = __builtin_bit_cast(float, w1.y << 16);
        cw[j][7] = __builtin_bit_cast(float, (int)(w1.y & 0xffff0000));
      }
#pragma unroll
      for (int cc = 0; cc < 2; ++cc) {
        const int ch = cc * 32 + clane;
        const int w2 = ch >> 4, cl = (ch & 15) * 5;
        float sk[4][5];
#pragma unroll
        for (int p = 0; p < 4; ++p)
#pragma unroll
          for (int k = 0; k < K; ++k)
            sk[p][k] = Sl[w2][4 * ch13 + p + k][cl + k];
#pragma unroll
        for (int p = 0; p < 4; ++p)
#pragma unroll
          for (int j = 0; j < 3; ++j) {
            float zv = 0.f;
#pragma unroll
            for (int k = 0; k < K; ++k) zv += cw[j][p + k] * sk[p][k];
            best[cc][j] = fmaxf(best[cc][j], zv);
          }
      }
    }
#pragma unroll
    for (int cc = 0; cc < 2; ++cc) {
      const float bc = ctxbias[cgi * 64 + cc * 32 + clane];
      float s = 0.f;
#pragma unroll
      for (int j = 0; j < 3; ++j) s += fmaxf(best[cc][j] + bc, 0.f);
      redf[cc * 256 + grp * 32 + clane] = s;
    }
    __syncthreads();
    if (tid < 64) {
      const int cc = tid >> 5, cl2 = tid & 31;
      float tot = 0.f;
#pragma unroll
      for (int g = 0; g < 8; ++g) tot += redf[cc * 256 + g * 32 + cl2];
      pbarH[((size_t)half * B + nb) * C + cgi * 64 + cc * 32 + cl2] = tot * (1.0f / Q);
    }
  }
}

// ---------------------------------------------------------------------------
// projfc: recompute the 192 FC outputs this block needs, then proj partial.
// pbar = sum of the two q'-half partials.
// ---------------------------------------------------------------------------
__global__ void projfc_k(const float* __restrict__ pooled, const float* __restrict__ pbarH,
                         const float* __restrict__ smfcwT, const float* __restrict__ smfcb,
                         const float* __restrict__ ctxfcwT, const float* __restrict__ ctxfcb,
                         const float* __restrict__ projT, float* __restrict__ partial) {
  __shared__ float rows[3 * C];
  __shared__ float cs[192];
  const int b = blockIdx.x, g = blockIdx.y, tid = threadIdx.x;
  for (int i = tid; i < C; i += 256) {
    rows[i] = pooled[(size_t)b * C + i];
    rows[C + i] = pooled[(size_t)(B + b) * C + i];
    rows[2 * C + i] = pbarH[(size_t)b * C + i] + pbarH[((size_t)B + b) * C + i];
  }
  __syncthreads();
  if (tid < 192) {
    const int j = g * 192 + tid;
    const int seg = j >> 9, h = j & 511;
    const float* WT = (seg == 2) ? ctxfcwT : smfcwT;
    const float* in = rows + seg * C;
    float acc = (seg == 2) ? ctxfcb[h] : smfcb[h];
    for (int c = 0; c < C; ++c) acc += in[c] * WT[(size_t)c * H + h];
    cs[tid] = acc;
  }
  __syncthreads();
  const int js = g * 192;
  float a0 = 0.f, a1 = 0.f;
  for (int j = 0; j < 192; ++j) {
    const float c = cs[j];
    a0 += c * projT[(size_t)(js + j) * P + tid];
    a1 += c * projT[(size_t)(js + j) * P + tid + 256];
  }
  partial[((size_t)g * B + b) * P + tid] = a0;
  partial[((size_t)g * B + b) * P + tid + 256] = a1;
}

// ---------------------------------------------------------------------------
// bnmid: sum proj partials; batch stats over B; tanh -> t.
// ---------------------------------------------------------------------------
__global__ void bnmid_k(const float* __restrict__ partial, const float* __restrict__ proj_b,
                        const float* __restrict__ gamma, const float* __restrict__ beta,
                        float* __restrict__ t) {
  __shared__ float s1[256], s2[256];
  const int pl = threadIdx.x & 63, rg = threadIdx.x >> 6;
  const int p = blockIdx.x * 64 + pl;
  const float pb = proj_b[p];
  float v[8];
#pragma unroll
  for (int i = 0; i < 8; ++i) {
    const int r = rg * 8 + i;
    float s = pb;
#pragma unroll
    for (int g = 0; g < NJ; ++g) s += partial[((size_t)g * B + r) * P + p];
    v[i] = s;
  }
  float a = 0.f;
#pragma unroll
  for (int i = 0; i < 8; ++i) a += v[i];
  s1[rg * 64 + pl] = a;
  __syncthreads();
  const float mu = (s1[pl] + s1[64 + pl] + s1[128 + pl] + s1[192 + pl]) * (1.0f / B);
  float b2 = 0.f;
#pragma unroll
  for (int i = 0; i < 8; ++i) { const float d = v[i] - mu; b2 += d * d; }
  s2[rg * 64 + pl] = b2;
  __syncthreads();
  const float var = (s2[pl] + s2[64 + pl] + s2[128 + pl] + s2[192 + pl]) * (1.0f / B);
  const float inv = rsqrtf(var + EPS_BN);
  const float g = gamma[p], be = beta[p];
#pragma unroll
  for (int i = 0; i < 8; ++i)
    t[(size_t)(rg * 8 + i) * P + p] = tanhf((v[i] - mu) * inv * g + be);
}

// ---------------------------------------------------------------------------
// final FC
// ---------------------------------------------------------------------------
__global__ void out_k(const float* __restrict__ t, const float* __restrict__ W,
                      const float* __restrict__ bias, float* __restrict__ out) {
  const int tid = threadIdx.x;  // 512
  const int o = tid >> 3, lane8 = tid & 7;
  const int bb = o >> 1, cl = o & 1;
  float acc = 0.f;
  for (int j = lane8; j < P; j += 8) acc += t[(size_t)bb * P + j] * W[cl * P + j];
#pragma unroll
  for (int off = 4; off; off >>= 1) acc += __shfl_down(acc, off);
  if (lane8 == 0) out[bb * NCLS + cl] = acc + bias[cl];
}

extern "C" void kernel_launch(void* const* d_in, const int* in_sizes, int n_in,
                              void* d_out, int out_size, void* d_ws, size_t ws_size,
                              hipStream_t stream) {
  const float* q       = (const float*)d_in[0];
  const float* a       = (const float*)d_in[1];
  const float* sm_w    = (const float*)d_in[2];
  const float* sm_b    = (const float*)d_in[3];
  const float* sm_fcw  = (const float*)d_in[4];
  const float* sm_fcb  = (const float*)d_in[5];
  const float* ctx_w   = (const float*)d_in[6];
  const float* ctx_b   = (const float*)d_in[7];
  const float* ctx_fcw = (const float*)d_in[8];
  const float* ctx_fcb = (const float*)d_in[9];
  const float* proj_w  = (const float*)d_in[10];
  const float* proj_b  = (const float*)d_in[11];
  const float* gamma   = (const float*)d_in[12];
  const float* beta    = (const float*)d_in[13];
  const float* out_w   = (const float*)d_in[14];
  const float* out_b   = (const float*)d_in[15];

  float* ws = (float*)d_ws;
  size_t off = 0;
  auto alloc = [&](size_t n) { float* p = ws + off; off += n; return p; };
  float* projT   = alloc((size_t)3 * H * P);
  float* smfcwT  = alloc((size_t)C * H);
  float* ctxfcwT = alloc((size_t)C * H);
  float* cosm    = alloc((size_t)B * Q * A);
  float* pooled  = alloc((size_t)2 * B * C);
  float* pbarH   = alloc((size_t)2 * B * C);
  float* partial = alloc((size_t)NJ * B * P);
  float* tbuf    = alloc((size_t)B * P);
  short* qb      = (short*)alloc((size_t)M * KP / 2);
  short* ab      = (short*)alloc((size_t)M * KP / 2);
  short* smb2    = (short*)alloc((size_t)CK * KP / 2);
  short* ctxb2   = (short*)alloc((size_t)CK * KP / 2);

  prep_k<<<NPAN + NCOS, 256, 0, stream>>>(q, a, sm_w, ctx_w, qb, ab, smb2, ctxb2, cosm);
  fused_k<<<2304, 256, 0, stream>>>(qb, ab, smb2, ctxb2, cosm, sm_b, ctx_b,
                                    proj_w, sm_fcw, ctx_fcw, projT, smfcwT, ctxfcwT,
                                    pooled, pbarH);
  projfc_k<<<dim3(B, NJ), 256, 0, stream>>>(pooled, pbarH, smfcwT, sm_fcb,
                                            ctxfcwT, ctx_fcb, projT, partial);
  bnmid_k<<<P / 64, 256, 0, stream>>>(partial, proj_b, gamma, beta, tbuf);
  out_k<<<1, 512, 0, stream>>>(tbuf, out_w, out_b, (float*)d_out);
}

// Round 15
// 82.906 us; speedup vs baseline: 1.2560x; 1.0716x over previous
//
#include <hip/hip_runtime.h>
#include <math.h>
#include <stdint.h>

namespace {
constexpr int B = 32, Q = 48, A = 48, D = 300;
constexpr int C = 512, K = 5, H = 512, P = 512, NCLS = 2;
constexpr int CK = C * K;         // 2560
constexpr int M = B * Q;          // 1536
constexpr int KP = 320;           // K padded for bf16 MFMA
constexpr float EPS_COS = 1e-6f, EPS_BN = 1e-5f;
constexpr int NPAN = 96 + 96 + 160 + 160;   // 512 16-row panels to convert
constexpr int NCOS = M / 4;                 // 384
constexpr int NJ = 8;                       // proj j-chunks
constexpr int PSZ = 40 * 16 * 8;            // 5120 shorts per panel
}
using short8 = __attribute__((ext_vector_type(8))) short;
using f32x4  = __attribute__((ext_vector_type(4))) float;

__device__ inline short f2bf(float v) {
  uint32_t u = __builtin_bit_cast(uint32_t, v);
  return (short)((u + 0x7fffu + ((u >> 16) & 1u)) >> 16);  // RNE
}

// ---------------------------------------------------------------------------
// prep: [0,512) fragment-major bf16 panel convert (LDS-staged, coalesced both
// sides) | [512,896) cosine sim
// ---------------------------------------------------------------------------
__global__ void prep_k(const float* __restrict__ q, const float* __restrict__ a,
                       const float* __restrict__ smw, const float* __restrict__ ctxw,
                       short* __restrict__ qb, short* __restrict__ ab,
                       short* __restrict__ smb, short* __restrict__ ctxb,
                       float* __restrict__ cosm) {
  __shared__ float sa[16 * 300];    // 19.2 KB panel stage
  __shared__ float4 qrow4[300];
  const int vb = blockIdx.x, tid = threadIdx.x;
  if (vb < NPAN) {
    const float* src; short* dst; int pl;
    if (vb < 96)       { src = q;    dst = qb;   pl = vb; }
    else if (vb < 192) { src = a;    dst = ab;   pl = vb - 96; }
    else if (vb < 352) { src = smw;  dst = smb;  pl = vb - 192; }
    else               { src = ctxw; dst = ctxb; pl = vb - 352; }
    const int row0 = pl * 16;
    for (int i = tid; i < 1200; i += 256) {
      const int r = i / 75, c4 = i - r * 75;
      const float4 v = *(const float4*)&src[(size_t)(row0 + r) * D + c4 * 4];
      *(float4*)&sa[r * 300 + c4 * 4] = v;
    }
    __syncthreads();
    for (int it = tid; it < 640; it += 256) {
      const int k8 = it >> 4, r = it & 15;
      short tmp[8];
#pragma unroll
      for (int e = 0; e < 8; ++e) {
        const int k = k8 * 8 + e;
        tmp[e] = (k < D) ? f2bf(sa[r * 300 + k]) : (short)0;
      }
      *(int4*)&dst[(size_t)pl * PSZ + (size_t)k8 * 128 + r * 8] = *(const int4*)tmp;
    }
  } else {
    const int b5 = vb - NPAN;
    const int qq = b5 * 4;            // 4 q-rows, same b (48 % 4 == 0)
    const int b = qq / Q;
    const float4* qp4 = (const float4*)(q + (size_t)qq * D);
    for (int i = tid; i < 300; i += 256) qrow4[i] = qp4[i];
    __syncthreads();
    const int sub = tid >> 6, lane = tid & 63;
    float qsq = 0.f;
    for (int i = lane; i < 75; i += 64) {
      float4 v = qrow4[sub * 75 + i];
      qsq += v.x * v.x + v.y * v.y + v.z * v.z + v.w * v.w;
    }
#pragma unroll
    for (int off2 = 32; off2; off2 >>= 1) qsq += __shfl_xor(qsq, off2);
    const float qn = sqrtf(qsq);
    if (lane < A) {
      const float4* ap4 = (const float4*)(a + ((size_t)b * A + lane) * D);
      float dot = 0.f, asq = 0.f;
      for (int i = 0; i < 75; ++i) {
        float4 av = ap4[i], qv = qrow4[sub * 75 + i];
        dot += qv.x * av.x + qv.y * av.y + qv.z * av.z + qv.w * av.w;
        asq += av.x * av.x + av.y * av.y + av.z * av.z + av.w * av.w;
      }
      cosm[(size_t)(qq + sub) * A + lane] = dot / fmaxf(qn * sqrtf(asq), EPS_COS);
    }
  }
}

// ---------------------------------------------------------------------------
// fused: [0,256) ctx GEMM+pool | [256,768) sm GEMM+pool | [768,2048) weight
// transposes.  Coalesced fragment-major loads, 3-deep prefetch (covers ~216
// cyc of MFMA >= L2 latency), fp32 S in padded LDS [4][56][81], bf16 cos.
// 80000 B LDS -> 2 blocks/CU (LDS-capped; VGPR bump to ~170 stays in the
// 129-256 bracket so occupancy is unchanged).
// ---------------------------------------------------------------------------
__global__ void __launch_bounds__(256)
fused_k(const short* __restrict__ qb, const short* __restrict__ ab,
        const short* __restrict__ smb, const short* __restrict__ ctxb,
        const float* __restrict__ cosm, const float* __restrict__ smbias,
        const float* __restrict__ ctxbias,
        const float* __restrict__ projw, const float* __restrict__ smfcw,
        const float* __restrict__ ctxfcw,
        float* __restrict__ projT, float* __restrict__ smfcwT,
        float* __restrict__ ctxfcwT,
        float* __restrict__ pooled, float* __restrict__ pbar) {
  __shared__ __align__(16) char Lraw[80000];
  const int vb = blockIdx.x, tid = threadIdx.x;

  if (vb >= 768) {  // ---------------- transpose blocks ----------------
    float (*tile)[33] = (float (*)[33])Lraw;
    const int vb2 = vb - 768;
    const int tx = tid & 31, ty = tid >> 5;
    if (vb2 < 768) {  // projT
      const int j0 = (vb2 % 48) * 32, p0 = (vb2 / 48) * 32;
      for (int i = ty; i < 32; i += 8)
        tile[i][tx] = projw[(size_t)(p0 + i) * (3 * H) + j0 + tx];
      __syncthreads();
      for (int i = ty; i < 32; i += 8)
        projT[(size_t)(j0 + i) * P + p0 + tx] = tile[tx][i];
    } else {
      const int b3 = vb2 - 768;
      const bool isC = b3 >= 256;
      const int b4 = isC ? b3 - 256 : b3;
      const float* W = isC ? ctxfcw : smfcw;
      float* WT = isC ? ctxfcwT : smfcwT;
      const int c0 = (b4 % 16) * 32, h0 = (b4 / 16) * 32;
      for (int i = ty; i < 32; i += 8)
        tile[i][tx] = W[(size_t)(h0 + i) * C + c0 + tx];
      __syncthreads();
      for (int i = ty; i < 32; i += 8)
        WT[(size_t)(c0 + i) * H + h0 + tx] = tile[tx][i];
    }
    return;
  }

  // ---------------- GEMM + pool blocks ----------------
  float (*Sl)[56][81] = (float (*)[56][81])Lraw;          // 72576 B
  short (*coslb)[56]  = (short (*)[56])(Lraw + 72576);    // 5376 B
  float* redf         = (float*)(Lraw + 77952);           // 2048 B
  const bool isCtx = vb < 256;
  const int lane = tid & 63, wv = tid >> 6;
  const int r16 = lane & 15, kq = lane >> 4;
  const int v2 = isCtx ? vb : vb - 256;
  const int nb = v2 >> 3, cgi = v2 & 7;   // ctx: nb=b 0..31; sm: nb 0..63

  const short* Xp = isCtx ? ab : ((nb < B) ? qb : ab);
  const int xp0 = (isCtx ? nb : ((nb < B) ? nb : nb - B)) * 3;
  const short* Wp = isCtx ? ctxb : smb;
  const int wp0 = cgi * 20 + wv * 5;
  const short* Xw = Xp + (size_t)xp0 * PSZ + kq * 128 + r16 * 8;
  const short* Ww = Wp + (size_t)wp0 * PSZ + kq * 128 + r16 * 8;

  for (int i = lane; i < 640; i += 64) {  // zero-pad rows 0..3, 52..55
    const int rr = i / 80, cc2 = i % 80;
    Sl[wv][rr < 4 ? rr : rr + 48][cc2] = 0.f;
  }
  if (isCtx) {  // stage cos rows (bf16), zero-padded position axis
    for (int i = tid; i < 48 * 56; i += 256) {
      const int qi = i / 56, p4 = i % 56;
      const float cv = (p4 >= 4 && p4 < 52)
                     ? cosm[((size_t)nb * Q + qi) * A + p4 - 4] : 0.f;
      coslb[qi][p4] = f2bf(cv);
    }
  }

  f32x4 acc[3][5];
#pragma unroll
  for (int mi = 0; mi < 3; ++mi)
#pragma unroll
    for (int ni = 0; ni < 5; ++ni) acc[mi][ni] = f32x4{0.f, 0.f, 0.f, 0.f};

  int4 cA0[3], cB0[5], cA1[3], cB1[5], cA2[3], cB2[5];
  auto issue = [&](int ks, int4* pA, int4* pB) {
#pragma unroll
    for (int i = 0; i < 3; ++i) pA[i] = *(const int4*)(Xw + (size_t)i * PSZ + ks * 512);
#pragma unroll
    for (int i = 0; i < 5; ++i) pB[i] = *(const int4*)(Ww + (size_t)i * PSZ + ks * 512);
  };
  auto domfma = [&](const int4* pA, const int4* pB) {
#pragma unroll
    for (int mi = 0; mi < 3; ++mi)
#pragma unroll
      for (int ni = 0; ni < 5; ++ni)
        acc[mi][ni] = __builtin_amdgcn_mfma_f32_16x16x32_bf16(
            __builtin_bit_cast(short8, pA[mi]),
            __builtin_bit_cast(short8, pB[ni]), acc[mi][ni], 0, 0, 0);
  };

  // 3-deep software pipeline over the 10 K-steps (static buffer rotation)
  issue(0, cA0, cB0);
  issue(1, cA1, cB1);
  issue(2, cA2, cB2);
  domfma(cA0, cB0); issue(3, cA0, cB0);
  domfma(cA1, cB1); issue(4, cA1, cB1);
  domfma(cA2, cB2); issue(5, cA2, cB2);
  domfma(cA0, cB0); issue(6, cA0, cB0);
  domfma(cA1, cB1); issue(7, cA1, cB1);
  domfma(cA2, cB2); issue(8, cA2, cB2);
  domfma(cA0, cB0); issue(9, cA0, cB0);
  domfma(cA1, cB1);
  domfma(cA2, cB2);
  domfma(cA0, cB0);

#pragma unroll
  for (int mi = 0; mi < 3; ++mi)
#pragma unroll
    for (int ni = 0; ni < 5; ++ni)
#pragma unroll
      for (int r = 0; r < 4; ++r)
        Sl[wv][mi * 16 + kq * 4 + r + 4][ni * 16 + r16] = acc[mi][ni][r];
  __syncthreads();

  if (!isCtx) {
    const int ch = tid & 63, part = tid >> 6;
    const int w2 = ch >> 4, cl = (ch & 15) * 5;
    float best = -1e30f;
#pragma unroll
    for (int j = 0; j < 13; ++j) {
      const int l = part * 13 + j;
      const float z = Sl[w2][l + 0][cl + 0] + Sl[w2][l + 1][cl + 1]
                    + Sl[w2][l + 2][cl + 2] + Sl[w2][l + 3][cl + 3]
                    + Sl[w2][l + 4][cl + 4];
      best = fmaxf(best, z);
    }
    redf[part * 64 + ch] = best;
    __syncthreads();
    if (tid < 64) {
      const float m = fmaxf(fmaxf(redf[tid], redf[64 + tid]),
                            fmaxf(redf[128 + tid], redf[192 + tid]));
      pooled[(size_t)nb * C + cgi * 64 + tid] =
          fmaxf(m + smbias[cgi * 64 + tid], 0.f);
    }
  } else {
    const int clane = tid & 31, grp = tid >> 5;
    float best[2][6];
#pragma unroll
    for (int cc = 0; cc < 2; ++cc)
#pragma unroll
      for (int j = 0; j < 6; ++j) best[cc][j] = -1e30f;
    for (int ch13 = 0; ch13 < 13; ++ch13) {
      float cw[6][8];
#pragma unroll
      for (int j = 0; j < 6; ++j) {
        const short* crow = &coslb[grp * 6 + j][4 * ch13];
        const int2 w0 = *(const int2*)crow;
        const int2 w1 = *(const int2*)(crow + 4);
        cw[j][0] = __builtin_bit_cast(float, w0.x << 16);
        cw[j][1] = __builtin_bit_cast(float, (int)(w0.x & 0xffff0000));
        cw[j][2] = __builtin_bit_cast(float, w0.y << 16);
        cw[j][3] = __builtin_bit_cast(float, (int)(w0.y & 0xffff0000));
        cw[j][4] = __builtin_bit_cast(float, w1.x << 16);
        cw[j][5] = __builtin_bit_cast(float, (int)(w1.x & 0xffff0000));
        cw[j][6] = __builtin_bit_cast(float, w1.y << 16);
        cw[j][7] = __builtin_bit_cast(float, (int)(w1.y & 0xffff0000));
      }
#pragma unroll
      for (int cc = 0; cc < 2; ++cc) {
        const int ch = cc * 32 + clane;
        const int w2 = ch >> 4, cl = (ch & 15) * 5;
        float sk[4][5];
#pragma unroll
        for (int p = 0; p < 4; ++p)
#pragma unroll
          for (int k = 0; k < K; ++k)
            sk[p][k] = Sl[w2][4 * ch13 + p + k][cl + k];
#pragma unroll
        for (int p = 0; p < 4; ++p)
#pragma unroll
          for (int j = 0; j < 6; ++j) {
            float zv = 0.f;
#pragma unroll
            for (int k = 0; k < K; ++k) zv += cw[j][p + k] * sk[p][k];
            best[cc][j] = fmaxf(best[cc][j], zv);
          }
      }
    }
#pragma unroll
    for (int cc = 0; cc < 2; ++cc) {
      const float bc = ctxbias[cgi * 64 + cc * 32 + clane];
      float s = 0.f;
#pragma unroll
      for (int j = 0; j < 6; ++j) s += fmaxf(best[cc][j] + bc, 0.f);
      redf[cc * 256 + grp * 32 + clane] = s;
    }
    __syncthreads();
    if (tid < 64) {
      const int cc = tid >> 5, cl2 = tid & 31;
      float tot = 0.f;
#pragma unroll
      for (int g = 0; g < 8; ++g) tot += redf[cc * 256 + g * 32 + cl2];
      pbar[(size_t)nb * C + cgi * 64 + cc * 32 + cl2] = tot * (1.0f / Q);
    }
  }
}

// ---------------------------------------------------------------------------
// projfc: recompute the 192 FC outputs this block needs, then proj partial.
// ---------------------------------------------------------------------------
__global__ void projfc_k(const float* __restrict__ pooled, const float* __restrict__ pbar,
                         const float* __restrict__ smfcwT, const float* __restrict__ smfcb,
                         const float* __restrict__ ctxfcwT, const float* __restrict__ ctxfcb,
                         const float* __restrict__ projT, float* __restrict__ partial) {
  __shared__ float rows[3 * C];
  __shared__ float cs[192];
  const int b = blockIdx.x, g = blockIdx.y, tid = threadIdx.x;
  for (int i = tid; i < C; i += 256) {
    rows[i] = pooled[(size_t)b * C + i];
    rows[C + i] = pooled[(size_t)(B + b) * C + i];
    rows[2 * C + i] = pbar[(size_t)b * C + i];
  }
  __syncthreads();
  if (tid < 192) {
    const int j = g * 192 + tid;
    const int seg = j >> 9, h = j & 511;
    const float* WT = (seg == 2) ? ctxfcwT : smfcwT;
    const float* in = rows + seg * C;
    float acc = (seg == 2) ? ctxfcb[h] : smfcb[h];
    for (int c = 0; c < C; ++c) acc += in[c] * WT[(size_t)c * H + h];
    cs[tid] = acc;
  }
  __syncthreads();
  const int js = g * 192;
  float a0 = 0.f, a1 = 0.f;
  for (int j = 0; j < 192; ++j) {
    const float c = cs[j];
    a0 += c * projT[(size_t)(js + j) * P + tid];
    a1 += c * projT[(size_t)(js + j) * P + tid + 256];
  }
  partial[((size_t)g * B + b) * P + tid] = a0;
  partial[((size_t)g * B + b) * P + tid + 256] = a1;
}

// ---------------------------------------------------------------------------
// bnmid: sum proj partials; batch stats over B; tanh -> t.
// ---------------------------------------------------------------------------
__global__ void bnmid_k(const float* __restrict__ partial, const float* __restrict__ proj_b,
                        const float* __restrict__ gamma, const float* __restrict__ beta,
                        float* __restrict__ t) {
  __shared__ float s1[256], s2[256];
  const int pl = threadIdx.x & 63, rg = threadIdx.x >> 6;
  const int p = blockIdx.x * 64 + pl;
  const float pb = proj_b[p];
  float v[8];
#pragma unroll
  for (int i = 0; i < 8; ++i) {
    const int r = rg * 8 + i;
    float s = pb;
#pragma unroll
    for (int g = 0; g < NJ; ++g) s += partial[((size_t)g * B + r) * P + p];
    v[i] = s;
  }
  float a = 0.f;
#pragma unroll
  for (int i = 0; i < 8; ++i) a += v[i];
  s1[rg * 64 + pl] = a;
  __syncthreads();
  const float mu = (s1[pl] + s1[64 + pl] + s1[128 + pl] + s1[192 + pl]) * (1.0f / B);
  float b2 = 0.f;
#pragma unroll
  for (int i = 0; i < 8; ++i) { const float d = v[i] - mu; b2 += d * d; }
  s2[rg * 64 + pl] = b2;
  __syncthreads();
  const float var = (s2[pl] + s2[64 + pl] + s2[128 + pl] + s2[192 + pl]) * (1.0f / B);
  const float inv = rsqrtf(var + EPS_BN);
  const float g = gamma[p], be = beta[p];
#pragma unroll
  for (int i = 0; i < 8; ++i)
    t[(size_t)(rg * 8 + i) * P + p] = tanhf((v[i] - mu) * inv * g + be);
}

// ---------------------------------------------------------------------------
// final FC
// ---------------------------------------------------------------------------
__global__ void out_k(const float* __restrict__ t, const float* __restrict__ W,
                      const float* __restrict__ bias, float* __restrict__ out) {
  const int tid = threadIdx.x;  // 512
  const int o = tid >> 3, lane8 = tid & 7;
  const int bb = o >> 1, cl = o & 1;
  float acc = 0.f;
  for (int j = lane8; j < P; j += 8) acc += t[(size_t)bb * P + j] * W[cl * P + j];
#pragma unroll
  for (int off = 4; off; off >>= 1) acc += __shfl_down(acc, off);
  if (lane8 == 0) out[bb * NCLS + cl] = acc + bias[cl];
}

extern "C" void kernel_launch(void* const* d_in, const int* in_sizes, int n_in,
                              void* d_out, int out_size, void* d_ws, size_t ws_size,
                              hipStream_t stream) {
  const float* q       = (const float*)d_in[0];
  const float* a       = (const float*)d_in[1];
  const float* sm_w    = (const float*)d_in[2];
  const float* sm_b    = (const float*)d_in[3];
  const float* sm_fcw  = (const float*)d_in[4];
  const float* sm_fcb  = (const float*)d_in[5];
  const float* ctx_w   = (const float*)d_in[6];
  const float* ctx_b   = (const float*)d_in[7];
  const float* ctx_fcw = (const float*)d_in[8];
  const float* ctx_fcb = (const float*)d_in[9];
  const float* proj_w  = (const float*)d_in[10];
  const float* proj_b  = (const float*)d_in[11];
  const float* gamma   = (const float*)d_in[12];
  const float* beta    = (const float*)d_in[13];
  const float* out_w   = (const float*)d_in[14];
  const float* out_b   = (const float*)d_in[15];

  float* ws = (float*)d_ws;
  size_t off = 0;
  auto alloc = [&](size_t n) { float* p = ws + off; off += n; return p; };
  float* projT   = alloc((size_t)3 * H * P);
  float* smfcwT  = alloc((size_t)C * H);
  float* ctxfcwT = alloc((size_t)C * H);
  float* cosm    = alloc((size_t)B * Q * A);
  float* pooled  = alloc((size_t)2 * B * C);
  float* pbar    = alloc((size_t)B * C);
  float* partial = alloc((size_t)NJ * B * P);
  float* tbuf    = alloc((size_t)B * P);
  short* qb      = (short*)alloc((size_t)M * KP / 2);
  short* ab      = (short*)alloc((size_t)M * KP / 2);
  short* smb2    = (short*)alloc((size_t)CK * KP / 2);
  short* ctxb2   = (short*)alloc((size_t)CK * KP / 2);

  prep_k<<<NPAN + NCOS, 256, 0, stream>>>(q, a, sm_w, ctx_w, qb, ab, smb2, ctxb2, cosm);
  fused_k<<<2048, 256, 0, stream>>>(qb, ab, smb2, ctxb2, cosm, sm_b, ctx_b,
                                    proj_w, sm_fcw, ctx_fcw, projT, smfcwT, ctxfcwT,
                                    pooled, pbar);
  projfc_k<<<dim3(B, NJ), 256, 0, stream>>>(pooled, pbar, smfcwT, sm_fcb,
                                            ctxfcwT, ctx_fcb, projT, partial);
  bnmid_k<<<P / 64, 256, 0, stream>>>(partial, proj_b, gamma, beta, tbuf);
  out_k<<<1, 512, 0, stream>>>(tbuf, out_w, out_b, (float*)d_out);
}